// Round 4
// baseline (199.912 us; speedup 1.0000x reference)
//
#include <hip/hip_runtime.h>

#define DIM 8192
#define BATCH 256
#define BN 32              // out-cols per block; grid = 256 blocks = 1/CU
#define KW 1024            // k-range per wave (8 waves partition K)
#define KS 32              // k per inner step (one MFMA-K)
#define NIT (KW / KS)      // 32 iterations per wave

typedef __attribute__((ext_vector_type(8))) short   short8;   // 8 bf16 (MFMA A/B frag)
typedef __attribute__((ext_vector_type(4))) float   f32x4;
typedef __attribute__((ext_vector_type(4))) unsigned short u16x4;

__device__ __forceinline__ unsigned short f2b(float f) {
    // round-to-nearest-even f32 -> bf16
    unsigned u = __builtin_bit_cast(unsigned, f);
    u = (u + 0x7FFFu + ((u >> 16) & 1u)) >> 16;
    return (unsigned short)u;
}

// ---- prepass: x f32 -> bf16 into workspace (4 MB) ----
__global__ __launch_bounds__(512) void cvt_x_kernel(const float* __restrict__ x,
                                                    unsigned short* __restrict__ xb) {
    int i = blockIdx.x * 512 + threadIdx.x;
    f32x4 v = reinterpret_cast<const f32x4*>(x)[i];
    u16x4 o;
    o[0] = f2b(v[0]); o[1] = f2b(v[1]); o[2] = f2b(v[2]); o[3] = f2b(v[3]);
    reinterpret_cast<u16x4*>(xb)[i] = o;
}

// ---- GEMM: out[b,i] = sum_j U[i,j] * x[b,j] ----
// Block = 32 U-rows (out cols) x full batch. 8 waves partition K: wave w owns
// k in [w*1024, (w+1)*1024). NO LDS / NO barriers in the main loop: each wave
// streams U (f32, cvt in-reg) and xb (bf16) independently -> 8 free-running
// latency-hiding streams per CU. U is read exactly once (col x K partition).
// End: 8 -> 1 K-reduction via a 3-barrier LDS tree (64 KB).
__global__ __launch_bounds__(512, 2) void gemm_kernel(const unsigned short* __restrict__ xb,
                                                      const float* __restrict__ U,
                                                      float* __restrict__ out) {
    __shared__ f32x4 red[4][1024];   // 4 slots x 16 KB = 64 KB

    const int tid  = threadIdx.x;
    const int lane = tid & 63;
    const int w    = tid >> 6;               // k-slice index 0..7
    const int n0   = blockIdx.x * BN;
    const int lr   = lane & 15;              // row-within-frag
    const int lk   = (lane >> 4) * 8;        // k-offset-within-frag

    // B (from U, f32): frag c: U-row = n0 + 16c + lr, k = w*KW + it*KS + lk + 0..7
    const float* Bp0 = U + (long)(n0 + lr) * DIM + w * KW + lk;
    const float* Bp1 = Bp0 + (long)16 * DIM;
    // A (from xb, bf16): frag a: batch row = 16a + lr, same k
    const unsigned short* Ap = xb + (long)lr * DIM + w * KW + lk;

    f32x4 acc[16][2];
#pragma unroll
    for (int a = 0; a < 16; ++a) {
        acc[a][0] = (f32x4){0.f, 0.f, 0.f, 0.f};
        acc[a][1] = (f32x4){0.f, 0.f, 0.f, 0.f};
    }

    for (int it = 0; it < NIT; ++it) {
        const int ko = it * KS;
        // B: 2 col-frags, f32 -> bf16 in registers
        f32x4 b0lo = *(const f32x4*)(Bp0 + ko);
        f32x4 b0hi = *(const f32x4*)(Bp0 + ko + 4);
        f32x4 b1lo = *(const f32x4*)(Bp1 + ko);
        f32x4 b1hi = *(const f32x4*)(Bp1 + ko + 4);
        short8 B0, B1;
#pragma unroll
        for (int j = 0; j < 4; ++j) {
            B0[j]     = (short)f2b(b0lo[j]);
            B0[j + 4] = (short)f2b(b0hi[j]);
            B1[j]     = (short)f2b(b1lo[j]);
            B1[j + 4] = (short)f2b(b1hi[j]);
        }
        // A: 16 batch-frags, each feeds 2 MFMAs
#pragma unroll
        for (int a = 0; a < 16; ++a) {
            short8 A = *(const short8*)(Ap + (long)a * (16 * DIM) + ko);
            acc[a][0] = __builtin_amdgcn_mfma_f32_16x16x32_bf16(A, B0, acc[a][0], 0, 0, 0);
            acc[a][1] = __builtin_amdgcn_mfma_f32_16x16x32_bf16(A, B1, acc[a][1], 0, 0, 0);
        }
    }

    // ---- K-reduction: 8 wave-partials -> wave 0, chunked (a=0..7, a=8..15)
    // slot layout: red[s][(a8*2 + c)*64 + lane] (16B/lane, stride-16B: conflict-free)
#pragma unroll
    for (int h = 0; h < 2; ++h) {
        if (w >= 4) {
#pragma unroll
            for (int a8 = 0; a8 < 8; ++a8) {
                red[w - 4][(a8 * 2 + 0) * 64 + lane] = acc[h * 8 + a8][0];
                red[w - 4][(a8 * 2 + 1) * 64 + lane] = acc[h * 8 + a8][1];
            }
        }
        __syncthreads();
        if (w < 4) {
#pragma unroll
            for (int a8 = 0; a8 < 8; ++a8) {
                acc[h * 8 + a8][0] += red[w][(a8 * 2 + 0) * 64 + lane];
                acc[h * 8 + a8][1] += red[w][(a8 * 2 + 1) * 64 + lane];
            }
        }
        __syncthreads();
    }
#pragma unroll
    for (int h = 0; h < 2; ++h) {
        if (w >= 1 && w < 4) {
#pragma unroll
            for (int a8 = 0; a8 < 8; ++a8) {
                red[w - 1][(a8 * 2 + 0) * 64 + lane] = acc[h * 8 + a8][0];
                red[w - 1][(a8 * 2 + 1) * 64 + lane] = acc[h * 8 + a8][1];
            }
        }
        __syncthreads();
        if (w == 0) {
#pragma unroll
            for (int s = 0; s < 3; ++s)
#pragma unroll
                for (int a8 = 0; a8 < 8; ++a8) {
                    acc[h * 8 + a8][0] += red[s][(a8 * 2 + 0) * 64 + lane];
                    acc[h * 8 + a8][1] += red[s][(a8 * 2 + 1) * 64 + lane];
                }
        }
        __syncthreads();
    }

    // ---- epilogue (wave 0 holds the full sum): D row=(l>>4)*4+r -> batch,
    //      col=l&15 -> out col (verified mapping from R1-R3)
    if (w == 0) {
#pragma unroll
        for (int a = 0; a < 16; ++a)
#pragma unroll
            for (int c = 0; c < 2; ++c) {
                float* o = out + (long)(16 * a + (lane >> 4) * 4) * DIM + n0 + 16 * c + lr;
#pragma unroll
                for (int r = 0; r < 4; ++r)
                    o[(long)r * DIM] = acc[a][c][r];
            }
    }
}

extern "C" void kernel_launch(void* const* d_in, const int* in_sizes, int n_in,
                              void* d_out, int out_size, void* d_ws, size_t ws_size,
                              hipStream_t stream) {
    const float* x = (const float*)d_in[0];     // [256, 8192] f32
    const float* U = (const float*)d_in[1];     // [8192, 8192] f32
    float* outp = (float*)d_out;                // [256, 8192] f32
    unsigned short* xb = (unsigned short*)d_ws; // 4 MB bf16 copy of x

    cvt_x_kernel<<<(BATCH * DIM / 4) / 512, 512, 0, stream>>>(x, xb);
    gemm_kernel<<<DIM / BN, 512, 0, stream>>>(xb, U, outp);
}

// Round 5
// 112.308 us; speedup vs baseline: 1.7800x; 1.7800x over previous
//
#include <hip/hip_runtime.h>

#define DIM 8192
#define BATCH 256
#define BN 64
#define BK 64
#define KSPLIT 4
#define KLEN (DIM / KSPLIT)   // 2048 k per block
#define NSTEP (KLEN / BK)     // 32 steps
#define NT (DIM / BN)         // 128 n-tiles

typedef __attribute__((ext_vector_type(8))) short   short8;   // 8 bf16 frag
typedef __attribute__((ext_vector_type(4))) float   f32x4;
typedef __attribute__((ext_vector_type(4))) unsigned short u16x4;

__device__ __forceinline__ unsigned short f2b(float f) {
    unsigned u = __builtin_bit_cast(unsigned, f);
    u = (u + 0x7FFFu + ((u >> 16) & 1u)) >> 16;
    return (unsigned short)u;
}

// ---- prepass: x f32 -> bf16 (ws+0, 4 MB) ----
__global__ __launch_bounds__(512) void cvt_x_kernel(const float* __restrict__ x,
                                                    unsigned short* __restrict__ xb) {
    int i = blockIdx.x * 512 + threadIdx.x;
    f32x4 v = reinterpret_cast<const f32x4*>(x)[i];
    u16x4 o;
    o[0] = f2b(v[0]); o[1] = f2b(v[1]); o[2] = f2b(v[2]); o[3] = f2b(v[3]);
    reinterpret_cast<u16x4*>(xb)[i] = o;
}

// LDS slot swizzle: slot16 = 16B unit index; XOR high bits into bank bits.
// Write conflicts (8 threads same U-row, g+4h in 0..7) -> spread over 8 bank
// groups; frag reads stay a bijection mod 16 within each 16-lane group.
__device__ __forceinline__ int F(int s) { return s ^ ((s >> 4) & 7); }

// ---- GEMM partials: p[ks][b][i] = sum_{j in ks-quarter} U[i,j]*x[b,j] ----
// grid 512 = 128 n-tiles x 4 k-quarters (2 blocks/CU), 512 threads (8 waves).
// BM=256 (full batch, U read exactly once), BN=64, BK=64.
// Wave w: batch rows [32w,32w+32), all 64 cols: 2(m) x 4(n) frags.
// B (U cols) staged f32->bf16 into double-buffered frag-linear LDS.
// A (xb bf16) loaded straight global->frag (L2/L3-hot).
__global__ __launch_bounds__(512, 4) void gemm_kernel(const unsigned short* __restrict__ xb,
                                                      const float* __restrict__ U,
                                                      float* __restrict__ part) {
    __shared__ unsigned short Blds[2][512 * 8];   // 2 bufs x 8KB, frag-linear

    const int tid  = threadIdx.x;
    const int lane = tid & 63;
    const int w    = tid >> 6;

    // XCD swizzle: xcd = bid%8 serves ks = xcd>>1 -> 1MB xb k-slab stays in its L2
    const int bid = blockIdx.x;
    const int x8  = bid & 7, j8 = bid >> 3;
    const int ks  = x8 >> 1;
    const int nt  = (x8 & 1) * 64 + j8;

    const int n0    = nt * BN;
    const int kbase = ks * KLEN;

    // --- B stager: thread -> (U-row r of 64, k-oct k8): 8 consecutive floats
    const int r  = tid >> 3;
    const int k8 = (tid & 7) * 8;
    const float* Up = U + (long)(n0 + r) * DIM + kbase + k8;          // + t*BK
    const int wslot = F(((r >> 4) * 2 + (k8 >> 5)) * 64 + (r & 15) + 16 * ((k8 >> 3) & 3));

    // --- A frags: lane l -> batch row 32w + mf*16 + (l&15), k = h*32 + (l>>4)*8
    const unsigned short* Ap = xb + (long)(32 * w + (lane & 15)) * DIM + kbase + (lane >> 4) * 8;

    // --- B frag read slots
    int rslot[4][2];
#pragma unroll
    for (int nf = 0; nf < 4; ++nf)
#pragma unroll
        for (int h = 0; h < 2; ++h)
            rslot[nf][h] = F((nf * 2 + h) * 64 + lane);

    f32x4 acc[2][4];
#pragma unroll
    for (int mf = 0; mf < 2; ++mf)
#pragma unroll
        for (int nf = 0; nf < 4; ++nf)
            acc[mf][nf] = (f32x4){0.f, 0.f, 0.f, 0.f};

    // ---- prologue: stage step 0 into buf0; prefetch A(0)
    f32x4 u0 = *(const f32x4*)(Up);
    f32x4 u1 = *(const f32x4*)(Up + 4);
    short8 Ac[2][2];
#pragma unroll
    for (int mf = 0; mf < 2; ++mf)
#pragma unroll
        for (int h = 0; h < 2; ++h)
            Ac[mf][h] = *(const short8*)(Ap + mf * 16 * DIM + h * 32);
    {
        short8 pk;
#pragma unroll
        for (int j = 0; j < 4; ++j) { pk[j] = (short)f2b(u0[j]); pk[j + 4] = (short)f2b(u1[j]); }
        *(short8*)&Blds[0][wslot * 8] = pk;
    }
    __syncthreads();

    for (int t = 0; t < NSTEP; ++t) {
        const int buf = t & 1;
        const int tn  = (t + 1 < NSTEP) ? t + 1 : t;   // clamped prefetch

        // prefetch next-step operands (global, independent)
        f32x4 un0 = *(const f32x4*)(Up + tn * BK);
        f32x4 un1 = *(const f32x4*)(Up + tn * BK + 4);
        short8 An[2][2];
#pragma unroll
        for (int mf = 0; mf < 2; ++mf)
#pragma unroll
            for (int h = 0; h < 2; ++h)
                An[mf][h] = *(const short8*)(Ap + tn * BK + mf * 16 * DIM + h * 32);

        // current step from LDS + registers
        short8 B[4][2];
#pragma unroll
        for (int nf = 0; nf < 4; ++nf)
#pragma unroll
            for (int h = 0; h < 2; ++h)
                B[nf][h] = *(const short8*)&Blds[buf][rslot[nf][h] * 8];

#pragma unroll
        for (int h = 0; h < 2; ++h)
#pragma unroll
            for (int mf = 0; mf < 2; ++mf)
#pragma unroll
                for (int nf = 0; nf < 4; ++nf)
                    acc[mf][nf] = __builtin_amdgcn_mfma_f32_16x16x32_bf16(
                        Ac[mf][h], B[nf][h], acc[mf][nf], 0, 0, 0);

        // stage next into other buffer
        {
            short8 pk;
#pragma unroll
            for (int j = 0; j < 4; ++j) { pk[j] = (short)f2b(un0[j]); pk[j + 4] = (short)f2b(un1[j]); }
            *(short8*)&Blds[buf ^ 1][wslot * 8] = pk;
        }
#pragma unroll
        for (int mf = 0; mf < 2; ++mf)
#pragma unroll
            for (int h = 0; h < 2; ++h)
                Ac[mf][h] = An[mf][h];

        __syncthreads();
    }

    // ---- partial store: D row=(l>>4)*4+reg, col=l&15 (verified mapping)
    float* p = part + (long)ks * (BATCH * DIM);
    const int prow0 = 32 * w + (lane >> 4) * 4;
    const int pcol0 = n0 + (lane & 15);
#pragma unroll
    for (int mf = 0; mf < 2; ++mf)
#pragma unroll
        for (int nf = 0; nf < 4; ++nf) {
            float* o = p + (long)(prow0 + mf * 16) * DIM + pcol0 + nf * 16;
#pragma unroll
            for (int rr = 0; rr < 4; ++rr)
                o[(long)rr * DIM] = acc[mf][nf][rr];
        }
}

// ---- reduce: out = p0 + p1 + p2 + p3 ----
__global__ __launch_bounds__(512) void reduce_kernel(const float* __restrict__ part,
                                                     float* __restrict__ out) {
    long i = (long)blockIdx.x * 512 + threadIdx.x;   // f32x4 index, 524288 total
    const f32x4* p0 = reinterpret_cast<const f32x4*>(part);
    const f32x4* p1 = p0 + (long)BATCH * DIM / 4;
    const f32x4* p2 = p1 + (long)BATCH * DIM / 4;
    const f32x4* p3 = p2 + (long)BATCH * DIM / 4;
    f32x4 v = p0[i] + p1[i] + p2[i] + p3[i];
    reinterpret_cast<f32x4*>(out)[i] = v;
}

// atomic fallback kernel path helper (used only if ws too small): adds partials
// directly; kept deterministic-enough (|err| << threshold). Not expected to run.
__global__ __launch_bounds__(512) void zero_kernel(float* __restrict__ out) {
    long i = (long)blockIdx.x * 512 + threadIdx.x;
    reinterpret_cast<f32x4*>(out)[i] = (f32x4){0.f, 0.f, 0.f, 0.f};
}

extern "C" void kernel_launch(void* const* d_in, const int* in_sizes, int n_in,
                              void* d_out, int out_size, void* d_ws, size_t ws_size,
                              hipStream_t stream) {
    const float* x = (const float*)d_in[0];     // [256, 8192] f32
    const float* U = (const float*)d_in[1];     // [8192, 8192] f32
    float* outp = (float*)d_out;                // [256, 8192] f32

    unsigned short* xb = (unsigned short*)d_ws;               // 4 MB
    float* part = (float*)((char*)d_ws + (size_t)BATCH * DIM * 2); // 32 MB

    cvt_x_kernel<<<(BATCH * DIM / 4) / 512, 512, 0, stream>>>(x, xb);

    const size_t need = (size_t)BATCH * DIM * 2 + (size_t)KSPLIT * BATCH * DIM * 4;
    if (ws_size >= need) {
        gemm_kernel<<<NT * KSPLIT, 512, 0, stream>>>(xb, U, part);
        reduce_kernel<<<(BATCH * DIM / 4) / 512, 512, 0, stream>>>(part, outp);
    } else {
        // fallback: accumulate straight into out (zero first). Partials are
        // written per-(ks) with non-overlapping adds via 4 sequential launches.
        zero_kernel<<<(BATCH * DIM / 4) / 512, 512, 0, stream>>>(outp);
        // reuse gemm into out via atomics would be nondeterministic; instead
        // run 4 sequential gemms each adding its quarter is not supported by
        // this kernel shape — emit partials into out in 4 chunks is invalid.
        // Practical fallback: single-partial path (KSPLIT blocks write disjoint
        // k-quarters summed with atomicAdd). Threshold (±9.16) dwarfs fp
        // reorder noise.
        gemm_kernel<<<NT * KSPLIT, 512, 0, stream>>>(xb, U, part); // will fault-free only if ws ok; ws expected >= need
        reduce_kernel<<<(BATCH * DIM / 4) / 512, 512, 0, stream>>>(part, outp);
    }
}

// Round 6
// 109.827 us; speedup vs baseline: 1.8202x; 1.0226x over previous
//
#include <hip/hip_runtime.h>

#define DIM 8192
#define BATCH 256
#define BN 64
#define BK 64
#define KSPLIT 4
#define KLEN (DIM / KSPLIT)   // 2048 k per block
#define NSTEP (KLEN / BK)     // 32 steps
#define NT (DIM / BN)         // 128 n-tiles

typedef __attribute__((ext_vector_type(8))) short   short8;   // 8 bf16 frag
typedef __attribute__((ext_vector_type(4))) float   f32x4;
typedef __attribute__((ext_vector_type(4))) unsigned short u16x4;

__device__ __forceinline__ unsigned short f2b(float f) {
    unsigned u = __builtin_bit_cast(unsigned, f);
    u = (u + 0x7FFFu + ((u >> 16) & 1u)) >> 16;
    return (unsigned short)u;
}

// ---- prepass: x f32 -> bf16 (ws+0, 4 MB) ----
__global__ __launch_bounds__(512) void cvt_x_kernel(const float* __restrict__ x,
                                                    unsigned short* __restrict__ xb) {
    int i = blockIdx.x * 512 + threadIdx.x;
    f32x4 v = reinterpret_cast<const f32x4*>(x)[i];
    u16x4 o;
    o[0] = f2b(v[0]); o[1] = f2b(v[1]); o[2] = f2b(v[2]); o[3] = f2b(v[3]);
    reinterpret_cast<u16x4*>(xb)[i] = o;
}

// LDS 16B-slot swizzle (verified conflict-free both sides in R5)
__device__ __forceinline__ int F(int s) { return s ^ ((s >> 4) & 7); }

// ---- GEMM partials: p[ks][b][i] = sum_{j in ks-quarter} U[i,j]*x[b,j] ----
// grid 512 = 128 n-tiles x 4 k-quarters (2 blocks/CU), 512 threads (8 waves).
// BM=256 (full batch, U read exactly once), BN=64, BK=64.
// T14 async-STAGE: U(t+2) issued at step t; cvt+ds_write of U(t+1) at step t
// uses data issued one FULL step earlier (slack ~3000cy >> HBM latency).
// A: distance-1 parity slots, issued at step top. 2-phase unroll, static idx.
__global__ __launch_bounds__(512, 4) void gemm_kernel(const unsigned short* __restrict__ xb,
                                                      const float* __restrict__ U,
                                                      float* __restrict__ part) {
    __shared__ unsigned short Blds[2][512 * 8];   // 2 bufs x 8KB, frag-linear

    const int tid  = threadIdx.x;
    const int lane = tid & 63;
    const int w    = tid >> 6;

    // XCD swizzle: xcd = bid%8 serves ks = xcd>>1 -> 1MB xb k-slab stays in its L2
    const int bid = blockIdx.x;
    const int x8  = bid & 7, j8 = bid >> 3;
    const int ks  = x8 >> 1;
    const int nt  = (x8 & 1) * 64 + j8;

    const int n0    = nt * BN;
    const int kbase = ks * KLEN;

    // --- B stager: thread -> (U-row r of 64, k-oct k8): 8 consecutive floats
    const int r  = tid >> 3;
    const int k8 = (tid & 7) * 8;
    const float* Up = U + (long)(n0 + r) * DIM + kbase + k8;          // + t*BK
    const int wslot = F(((r >> 4) * 2 + (k8 >> 5)) * 64 + (r & 15) + 16 * ((k8 >> 3) & 3));

    // --- A frags: lane l -> batch row 32w + mf*16 + (l&15), k = h*32 + (l>>4)*8
    const unsigned short* Ap = xb + (long)(32 * w + (lane & 15)) * DIM + kbase + (lane >> 4) * 8;

    // --- B frag read slots
    int rslot[4][2];
#pragma unroll
    for (int nf = 0; nf < 4; ++nf)
#pragma unroll
        for (int h = 0; h < 2; ++h)
            rslot[nf][h] = F((nf * 2 + h) * 64 + lane);

    f32x4 acc[2][4];
#pragma unroll
    for (int mf = 0; mf < 2; ++mf)
#pragma unroll
        for (int nf = 0; nf < 4; ++nf)
            acc[mf][nf] = (f32x4){0.f, 0.f, 0.f, 0.f};

    f32x4  Upre[2][2];   // U(s) lives in slot s&1
    short8 Aq[2][4];     // A(s) lives in slot s&1; frag idx = mf*2+h

    // ---- prologue: U(0)->LDS buf0 directly; U(1)->Upre[1]; A(0)->Aq[0]
    {
        f32x4 u0 = *(const f32x4*)(Up);
        f32x4 u1 = *(const f32x4*)(Up + 4);
        Upre[1][0] = *(const f32x4*)(Up + BK);
        Upre[1][1] = *(const f32x4*)(Up + BK + 4);
#pragma unroll
        for (int mf = 0; mf < 2; ++mf)
#pragma unroll
            for (int h = 0; h < 2; ++h)
                Aq[0][mf * 2 + h] = *(const short8*)(Ap + mf * 16 * DIM + h * 32);
        short8 pk;
#pragma unroll
        for (int j = 0; j < 4; ++j) { pk[j] = (short)f2b(u0[j]); pk[j + 4] = (short)f2b(u1[j]); }
        *(short8*)&Blds[0][wslot * 8] = pk;
    }
    __syncthreads();

    // step T (P=T&1, Q=P^1): issue U(T+2)->Upre[P], A(T+1)->Aq[Q];
    // cvt+write U(T+1) from Upre[Q] -> buf Q; read B(T) from buf P; MFMA; barrier.
#define STEPBODY(T, P, Q)                                                            \
    do {                                                                             \
        { int tp = ((T) + 2 < NSTEP) ? (T) + 2 : NSTEP - 1;                          \
          Upre[P][0] = *(const f32x4*)(Up + tp * BK);                                \
          Upre[P][1] = *(const f32x4*)(Up + tp * BK + 4); }                          \
        { int ta = ((T) + 1 < NSTEP) ? (T) + 1 : NSTEP - 1;                          \
          Aq[Q][0] = *(const short8*)(Ap + ta * BK);                                 \
          Aq[Q][1] = *(const short8*)(Ap + ta * BK + 32);                            \
          Aq[Q][2] = *(const short8*)(Ap + ta * BK + 16 * DIM);                      \
          Aq[Q][3] = *(const short8*)(Ap + ta * BK + 16 * DIM + 32); }               \
        {                                                                            \
            short8 pk;                                                               \
            _Pragma("unroll")                                                        \
            for (int j = 0; j < 4; ++j) {                                            \
                pk[j]     = (short)f2b(Upre[Q][0][j]);                               \
                pk[j + 4] = (short)f2b(Upre[Q][1][j]);                               \
            }                                                                        \
            *(short8*)&Blds[Q][wslot * 8] = pk;                                      \
        }                                                                            \
        {                                                                            \
            short8 B0[4];                                                            \
            _Pragma("unroll")                                                        \
            for (int nf = 0; nf < 4; ++nf) B0[nf] = *(const short8*)&Blds[P][rslot[nf][0] * 8]; \
            __builtin_amdgcn_s_setprio(1);                                           \
            _Pragma("unroll")                                                        \
            for (int mf = 0; mf < 2; ++mf)                                           \
                _Pragma("unroll")                                                    \
                for (int nf = 0; nf < 4; ++nf)                                       \
                    acc[mf][nf] = __builtin_amdgcn_mfma_f32_16x16x32_bf16(           \
                        Aq[P][mf * 2 + 0], B0[nf], acc[mf][nf], 0, 0, 0);            \
            __builtin_amdgcn_s_setprio(0);                                           \
            short8 B1[4];                                                            \
            _Pragma("unroll")                                                        \
            for (int nf = 0; nf < 4; ++nf) B1[nf] = *(const short8*)&Blds[P][rslot[nf][1] * 8]; \
            __builtin_amdgcn_s_setprio(1);                                           \
            _Pragma("unroll")                                                        \
            for (int mf = 0; mf < 2; ++mf)                                           \
                _Pragma("unroll")                                                    \
                for (int nf = 0; nf < 4; ++nf)                                       \
                    acc[mf][nf] = __builtin_amdgcn_mfma_f32_16x16x32_bf16(           \
                        Aq[P][mf * 2 + 1], B1[nf], acc[mf][nf], 0, 0, 0);            \
            __builtin_amdgcn_s_setprio(0);                                           \
        }                                                                            \
        __syncthreads();                                                             \
    } while (0)

    for (int tt = 0; tt < NSTEP; tt += 2) {
        STEPBODY(tt,     0, 1);
        STEPBODY(tt + 1, 1, 0);
    }
#undef STEPBODY

    // ---- partial store: D row=(l>>4)*4+reg, col=l&15 (verified mapping)
    float* p = part + (long)ks * (BATCH * DIM);
    const int prow0 = 32 * w + (lane >> 4) * 4;
    const int pcol0 = n0 + (lane & 15);
#pragma unroll
    for (int mf = 0; mf < 2; ++mf)
#pragma unroll
        for (int nf = 0; nf < 4; ++nf) {
            float* o = p + (long)(prow0 + mf * 16) * DIM + pcol0 + nf * 16;
#pragma unroll
            for (int rr = 0; rr < 4; ++rr)
                o[(long)rr * DIM] = acc[mf][nf][rr];
        }
}

// ---- reduce: out = p0 + p1 + p2 + p3 ----
__global__ __launch_bounds__(512) void reduce_kernel(const float* __restrict__ part,
                                                     float* __restrict__ out) {
    long i = (long)blockIdx.x * 512 + threadIdx.x;   // f32x4 index, 524288 total
    const f32x4* p0 = reinterpret_cast<const f32x4*>(part);
    const f32x4* p1 = p0 + (long)BATCH * DIM / 4;
    const f32x4* p2 = p1 + (long)BATCH * DIM / 4;
    const f32x4* p3 = p2 + (long)BATCH * DIM / 4;
    f32x4 v = p0[i] + p1[i] + p2[i] + p3[i];
    reinterpret_cast<f32x4*>(out)[i] = v;
}

extern "C" void kernel_launch(void* const* d_in, const int* in_sizes, int n_in,
                              void* d_out, int out_size, void* d_ws, size_t ws_size,
                              hipStream_t stream) {
    const float* x = (const float*)d_in[0];     // [256, 8192] f32
    const float* U = (const float*)d_in[1];     // [8192, 8192] f32
    float* outp = (float*)d_out;                // [256, 8192] f32

    unsigned short* xb = (unsigned short*)d_ws;                    // 4 MB
    float* part = (float*)((char*)d_ws + (size_t)BATCH * DIM * 2); // 32 MB

    cvt_x_kernel<<<(BATCH * DIM / 4) / 512, 512, 0, stream>>>(x, xb);
    gemm_kernel<<<NT * KSPLIT, 512, 0, stream>>>(xb, U, part);
    reduce_kernel<<<(BATCH * DIM / 4) / 512, 512, 0, stream>>>(part, outp);
}

// Round 7
// 105.876 us; speedup vs baseline: 1.8882x; 1.0373x over previous
//
#include <hip/hip_runtime.h>

#define DIM 8192
#define BATCH 256
#define BN 64
#define BK 64
#define KSPLIT 4
#define KLEN (DIM / KSPLIT)   // 2048 k per block
#define NSTEP (KLEN / BK)     // 32 steps
#define NT (DIM / BN)         // 128 n-tiles

typedef __attribute__((ext_vector_type(8))) short   short8;   // 8 bf16 frag
typedef __attribute__((ext_vector_type(4))) float   f32x4;
typedef __attribute__((ext_vector_type(4))) unsigned short u16x4;

__device__ __forceinline__ unsigned short f2b(float f) {
    unsigned u = __builtin_bit_cast(unsigned, f);
    u = (u + 0x7FFFu + ((u >> 16) & 1u)) >> 16;
    return (unsigned short)u;
}

#define WAITL0 asm volatile("s_waitcnt lgkmcnt(0)" ::: "memory")
#define CFENCE asm volatile("" ::: "memory")

// ---- prepass: x f32 -> bf16 (ws+0, 4 MB) ----
__global__ __launch_bounds__(512) void cvt_x_kernel(const float* __restrict__ x,
                                                    unsigned short* __restrict__ xb) {
    int i = blockIdx.x * 512 + threadIdx.x;
    f32x4 v = reinterpret_cast<const f32x4*>(x)[i];
    u16x4 o;
    o[0] = f2b(v[0]); o[1] = f2b(v[1]); o[2] = f2b(v[2]); o[3] = f2b(v[3]);
    reinterpret_cast<u16x4*>(xb)[i] = o;
}

// LDS 16B-slot swizzle (verified conflict-free both sides, R5/R6)
__device__ __forceinline__ int F(int s) { return s ^ ((s >> 4) & 7); }

// ---- GEMM partials: p[ks][b][i] = sum_{j in ks-quarter} U[i,j]*x[b,j] ----
// grid 512 = 128 n-tiles x 4 k-quarters (2 blocks/CU), 512 threads (8 waves).
// Sync discipline: raw s_barrier + lgkmcnt(0) ONLY — no vmcnt(0) drain, so the
// global-load FIFO (U(t+2), A(t+1)) persists across barriers; compiler emits
// counted vmcnt waits before each use (its default fine-grained behavior).
__global__ __launch_bounds__(512, 4) void gemm_kernel(const unsigned short* __restrict__ xb,
                                                      const float* __restrict__ U,
                                                      float* __restrict__ part) {
    __shared__ unsigned short Blds[2][512 * 8];   // 2 bufs x 8KB, frag-linear

    const int tid  = threadIdx.x;
    const int lane = tid & 63;
    const int w    = tid >> 6;

    // XCD swizzle: bid&7 -> XCD; each XCD serves one (ks, nt-half): 1MB xb slab/L2
    const int bid = blockIdx.x;
    const int x8  = bid & 7, j8 = bid >> 3;
    const int ks  = x8 >> 1;
    const int nt  = (x8 & 1) * 64 + j8;

    const int n0    = nt * BN;
    const int kbase = ks * KLEN;

    // --- B stager: thread -> (U-row r of 64, k-oct k8): 8 consecutive floats
    const int r  = tid >> 3;
    const int k8 = (tid & 7) * 8;
    const float* Up = U + (long)(n0 + r) * DIM + kbase + k8;          // + t*BK
    const int wslot = F(((r >> 4) * 2 + (k8 >> 5)) * 64 + (r & 15) + 16 * ((k8 >> 3) & 3));

    // --- A frags: lane l -> batch row 32w + mf*16 + (l&15), k = h*32 + (l>>4)*8
    const unsigned short* Ap = xb + (long)(32 * w + (lane & 15)) * DIM + kbase + (lane >> 4) * 8;

    // --- B frag read slots
    int rslot[4][2];
#pragma unroll
    for (int nf = 0; nf < 4; ++nf)
#pragma unroll
        for (int h = 0; h < 2; ++h)
            rslot[nf][h] = F((nf * 2 + h) * 64 + lane);

    f32x4 acc[2][4];
#pragma unroll
    for (int mf = 0; mf < 2; ++mf)
#pragma unroll
        for (int nf = 0; nf < 4; ++nf)
            acc[mf][nf] = (f32x4){0.f, 0.f, 0.f, 0.f};

    f32x4  Upre[2][2];   // U(s) in slot s&1 (distance 2, HBM)
    short8 Aq[4];        // A(t) single set (distance 1, L2-hot; reissued post-MFMA)

    // ---- prologue: U(0)->buf0 directly; U(1)->Upre[1]; A(0)->Aq
    {
        f32x4 u0 = *(const f32x4*)(Up);
        f32x4 u1 = *(const f32x4*)(Up + 4);
        Upre[1][0] = *(const f32x4*)(Up + BK);
        Upre[1][1] = *(const f32x4*)(Up + BK + 4);
        Aq[0] = *(const short8*)(Ap);
        Aq[1] = *(const short8*)(Ap + 32);
        Aq[2] = *(const short8*)(Ap + 16 * DIM);
        Aq[3] = *(const short8*)(Ap + 16 * DIM + 32);
        short8 pk;
#pragma unroll
        for (int j = 0; j < 4; ++j) { pk[j] = (short)f2b(u0[j]); pk[j + 4] = (short)f2b(u1[j]); }
        *(short8*)&Blds[0][wslot * 8] = pk;
    }
    WAITL0;
    __builtin_amdgcn_s_barrier();
    CFENCE;

    // step T (P=T&1, Q=P^1):
    //  issue U(T+2)->Upre[P] | cvt Upre[Q]=U(T+1) -> ds_write buf Q
    //  | ds_read B(T) from buf P | MFMA | issue A(T+1)->Aq | lgkm0 | s_barrier
#define STEPBODY(T, P, Q)                                                            \
    do {                                                                             \
        { int tp = ((T) + 2 < NSTEP) ? (T) + 2 : NSTEP - 1;                          \
          Upre[P][0] = *(const f32x4*)(Up + tp * BK);                                \
          Upre[P][1] = *(const f32x4*)(Up + tp * BK + 4); }                          \
        {                                                                            \
            short8 pk;                                                               \
            _Pragma("unroll")                                                        \
            for (int j = 0; j < 4; ++j) {                                            \
                pk[j]     = (short)f2b(Upre[Q][0][j]);                               \
                pk[j + 4] = (short)f2b(Upre[Q][1][j]);                               \
            }                                                                        \
            *(short8*)&Blds[Q][wslot * 8] = pk;                                      \
        }                                                                            \
        {                                                                            \
            short8 B0[4];                                                            \
            _Pragma("unroll")                                                        \
            for (int nf = 0; nf < 4; ++nf) B0[nf] = *(const short8*)&Blds[P][rslot[nf][0] * 8]; \
            __builtin_amdgcn_s_setprio(1);                                           \
            _Pragma("unroll")                                                        \
            for (int mf = 0; mf < 2; ++mf)                                           \
                _Pragma("unroll")                                                    \
                for (int nf = 0; nf < 4; ++nf)                                       \
                    acc[mf][nf] = __builtin_amdgcn_mfma_f32_16x16x32_bf16(           \
                        Aq[mf * 2], B0[nf], acc[mf][nf], 0, 0, 0);                   \
            __builtin_amdgcn_s_setprio(0);                                           \
            short8 B1[4];                                                            \
            _Pragma("unroll")                                                        \
            for (int nf = 0; nf < 4; ++nf) B1[nf] = *(const short8*)&Blds[P][rslot[nf][1] * 8]; \
            __builtin_amdgcn_s_setprio(1);                                           \
            _Pragma("unroll")                                                        \
            for (int mf = 0; mf < 2; ++mf)                                           \
                _Pragma("unroll")                                                    \
                for (int nf = 0; nf < 4; ++nf)                                       \
                    acc[mf][nf] = __builtin_amdgcn_mfma_f32_16x16x32_bf16(           \
                        Aq[mf * 2 + 1], B1[nf], acc[mf][nf], 0, 0, 0);               \
            __builtin_amdgcn_s_setprio(0);                                           \
        }                                                                            \
        { int ta = ((T) + 1 < NSTEP) ? (T) + 1 : NSTEP - 1;                          \
          Aq[0] = *(const short8*)(Ap + ta * BK);                                    \
          Aq[1] = *(const short8*)(Ap + ta * BK + 32);                               \
          Aq[2] = *(const short8*)(Ap + ta * BK + 16 * DIM);                         \
          Aq[3] = *(const short8*)(Ap + ta * BK + 16 * DIM + 32); }                  \
        WAITL0;                                                                      \
        __builtin_amdgcn_s_barrier();                                                \
        CFENCE;                                                                      \
    } while (0)

    for (int tt = 0; tt < NSTEP; tt += 2) {
        STEPBODY(tt,     0, 1);
        STEPBODY(tt + 1, 1, 0);
    }
#undef STEPBODY

    // ---- partial store: D row=(l>>4)*4+reg, col=l&15 (verified mapping)
    float* p = part + (long)ks * (BATCH * DIM);
    const int prow0 = 32 * w + (lane >> 4) * 4;
    const int pcol0 = n0 + (lane & 15);
#pragma unroll
    for (int mf = 0; mf < 2; ++mf)
#pragma unroll
        for (int nf = 0; nf < 4; ++nf) {
            float* o = p + (long)(prow0 + mf * 16) * DIM + pcol0 + nf * 16;
#pragma unroll
            for (int rr = 0; rr < 4; ++rr)
                o[(long)rr * DIM] = acc[mf][nf][rr];
        }
}

// ---- reduce: out = p0 + p1 + p2 + p3 ----
__global__ __launch_bounds__(512) void reduce_kernel(const float* __restrict__ part,
                                                     float* __restrict__ out) {
    long i = (long)blockIdx.x * 512 + threadIdx.x;   // f32x4 index, 524288 total
    const f32x4* p0 = reinterpret_cast<const f32x4*>(part);
    const f32x4* p1 = p0 + (long)BATCH * DIM / 4;
    const f32x4* p2 = p1 + (long)BATCH * DIM / 4;
    const f32x4* p3 = p2 + (long)BATCH * DIM / 4;
    f32x4 v = p0[i] + p1[i] + p2[i] + p3[i];
    reinterpret_cast<f32x4*>(out)[i] = v;
}

extern "C" void kernel_launch(void* const* d_in, const int* in_sizes, int n_in,
                              void* d_out, int out_size, void* d_ws, size_t ws_size,
                              hipStream_t stream) {
    const float* x = (const float*)d_in[0];     // [256, 8192] f32
    const float* U = (const float*)d_in[1];     // [8192, 8192] f32
    float* outp = (float*)d_out;                // [256, 8192] f32

    unsigned short* xb = (unsigned short*)d_ws;                    // 4 MB
    float* part = (float*)((char*)d_ws + (size_t)BATCH * DIM * 2); // 32 MB

    cvt_x_kernel<<<(BATCH * DIM / 4) / 512, 512, 0, stream>>>(x, xb);
    gemm_kernel<<<NT * KSPLIT, 512, 0, stream>>>(xb, U, part);
    reduce_kernel<<<(BATCH * DIM / 4) / 512, 512, 0, stream>>>(part, outp);
}